// Round 3
// baseline (604.347 us; speedup 1.0000x reference)
//
#include <hip/hip_runtime.h>

typedef __bf16 bf16_t;
typedef bf16_t bf16x8 __attribute__((ext_vector_type(8)));
typedef float f32x4 __attribute__((ext_vector_type(4)));

#define BATCH 16384
#define HID 256

// ---------- bf16 helpers (manual RNE, no header dependency) ----------
__device__ __forceinline__ ushort f2b(float f) {
  union { float f; unsigned u; } v; v.f = f;
  unsigned u = v.u;
  unsigned r = (u + 0x7fffu + ((u >> 16) & 1u)) >> 16;
  return (ushort)r;
}
__device__ __forceinline__ float b2f(ushort u) {
  union { unsigned u; float f; } v; v.u = ((unsigned)u) << 16; return v.f;
}
__device__ __forceinline__ void loadbf4(const ushort* __restrict__ p, float* o) {
  uint2 q = *(const uint2*)p;
  o[0] = b2f((ushort)(q.x & 0xffffu));
  o[1] = b2f((ushort)(q.x >> 16));
  o[2] = b2f((ushort)(q.y & 0xffffu));
  o[3] = b2f((ushort)(q.y >> 16));
}
__device__ __forceinline__ uint2 packbf4(const float* v) {
  uint2 q;
  q.x = (unsigned)f2b(v[0]) | ((unsigned)f2b(v[1]) << 16);
  q.y = (unsigned)f2b(v[2]) | ((unsigned)f2b(v[3]) << 16);
  return q;
}

// ---------- convert fp32 -> bf16 (x and h in one launch) ----------
__global__ __launch_bounds__(256)
void f2b2_kernel(const float* __restrict__ a, const float* __restrict__ b,
                 ushort* __restrict__ oa, ushort* __restrict__ ob) {
  int bid = blockIdx.x;
  const float* in = (bid < 4096) ? a : b;
  ushort* out     = (bid < 4096) ? oa : ob;
  int t = (bid & 4095) * 256 + threadIdx.x;
  float4 v = *(const float4*)(in + (size_t)t * 4);
  float q[4] = {v.x, v.y, v.z, v.w};
  *(uint2*)(out + (size_t)t * 4) = packbf4(q);
}

// ---------- build transposed bf16 weights: Wt[ksel*256+d][h] = W[ksel][h][d] ----------
__global__ __launch_bounds__(256)
void wt2_kernel(const float* __restrict__ L, const float* __restrict__ R,
                ushort* __restrict__ Lt, ushort* __restrict__ Rt) {
  int bid = blockIdx.x;
  const float* W = (bid < 1024) ? L : R;
  ushort* Wt     = (bid < 1024) ? Lt : Rt;
  int idx = (bid & 1023) * 256 + threadIdx.x;
  int c = idx >> 8, hh = idx & 255;
  int ks = c >> 8, d = c & 255;
  Wt[idx] = f2b(W[ks * 65536 + hh * 256 + d]);
}

// ---------- fused GEMM: P[M,N] = A@W (+ optional K-concat: A1@W1 + A2@W2) ----------
// 128x128 tile, BK=64 double-buffered, STAGE(next)-before-COMPUTE(cur) 2-phase pipeline,
// global_load_lds(16B), XOR granule swizzle both-sides, per-job XCD-bijective block swizzle.
// Epilogues: 0=raw bf16, 1=+bias bf16 (cand), 2=sigmoid (z1/r/gnode slots 0,1,2).
// NOTE macro hygiene: all macro args are snapshotted into fresh locals (bufc/kts) and
// inner loop variables are uniquely named (i_s, kk_c, fr_c) — COMPUTE(t&1) with an inner
// loop named t caused a capture bug in the previous revision.
struct GJob {
  const ushort* A1; const ushort* A2;   // A2 != null => K=512 concat (8 steps)
  const ushort* B1; const ushort* B2;   // B2 used for kt>=4
  ushort* out;
  const float* bias;
  float* gnode; ushort* z1b; ushort* rb;   // epi 2 only
  int nx;        // column tiles (4 -> N=512, 8 -> N=1024)
  int epi;
  int nblocks;   // nx * 128
};

__global__ __launch_bounds__(256, 2)
void fgemm_kernel(GJob j0, GJob j1, int split) {
  __shared__ __align__(16) ushort As[2][128 * 64];
  __shared__ __align__(16) ushort Bs[2][128 * 64];

  const int bid  = blockIdx.x;
  const GJob j   = (bid < split) ? j0 : j1;
  const int lbid = (bid < split) ? bid : bid - split;

  const int tid  = threadIdx.x;
  const int lane = tid & 63;
  const int wave = tid >> 6;

  // per-job XCD-bijective swizzle (nblocks % 8 == 0 for all jobs; split % 8 == 0)
  const int q   = j.nblocks >> 3;
  const int id2 = (lbid & 7) * q + (lbid >> 3);
  int cn, cm;
  if (j.nx == 8) { cn = id2 & 7; cm = id2 >> 3; }
  else           { cn = id2 & 3; cm = id2 >> 2; }
  const int bm = cm * 128;
  const int bn = cn * 128;

  const int wm   = (wave >> 1) * 64;
  const int wn   = (wave & 1) * 64;
  const int row  = lane & 15;
  const int quad = lane >> 4;

  // staging geometry: 16 chunks of 1KB (8 rows x 64 bf16); wave w owns chunks w*4..w*4+3
  const int r_s = lane >> 3;
  const int g_s = lane & 7;
  const int gsw = g_s ^ r_s;   // inverse-swizzled source granule

  f32x4 acc[4][4] = {};

#define STAGE(buf, kt)                                                             \
  {                                                                                \
    const int bufs = (buf);                                                        \
    const int kts  = (kt);                                                         \
    const ushort* Ab = (kts < 4) ? j.A1 : j.A2;                                    \
    const ushort* Bb = (kts < 4) ? j.B1 : j.B2;                                    \
    const int k0 = (kts & 3) * 64;                                                 \
    for (int i_s = 0; i_s < 4; ++i_s) {                                            \
      const int ci = wave * 4 + i_s;                                               \
      const int r  = ci * 8 + r_s;                                                 \
      __builtin_amdgcn_global_load_lds(                                            \
          (const __attribute__((address_space(1))) void*)(Ab + (size_t)(bm + r) * 256 + k0 + gsw * 8), \
          (__attribute__((address_space(3))) void*)&As[bufs][ci * 512], 16, 0, 0); \
      __builtin_amdgcn_global_load_lds(                                            \
          (const __attribute__((address_space(1))) void*)(Bb + (size_t)(bn + r) * 256 + k0 + gsw * 8), \
          (__attribute__((address_space(3))) void*)&Bs[bufs][ci * 512], 16, 0, 0); \
    }                                                                              \
  }

#define COMPUTE(buf)                                                               \
  {                                                                                \
    const int bufc = (buf);                                                        \
    bf16x8 af[2][4], bfr[2][4];                                                    \
    for (int kk_c = 0; kk_c < 2; ++kk_c)                                           \
      for (int fr_c = 0; fr_c < 4; ++fr_c) {                                       \
        const int ar = wm + fr_c * 16 + row;                                       \
        const int ga = (kk_c * 4 + quad) ^ (ar & 7);                               \
        af[kk_c][fr_c] = *(const bf16x8*)&As[bufc][ar * 64 + ga * 8];              \
        const int br = wn + fr_c * 16 + row;                                       \
        const int gb = (kk_c * 4 + quad) ^ (br & 7);                               \
        bfr[kk_c][fr_c] = *(const bf16x8*)&Bs[bufc][br * 64 + gb * 8];             \
      }                                                                            \
    for (int kk_c = 0; kk_c < 2; ++kk_c)                                           \
      for (int ti = 0; ti < 4; ++ti)                                               \
        for (int tj = 0; tj < 4; ++tj)                                             \
          acc[ti][tj] = __builtin_amdgcn_mfma_f32_16x16x32_bf16(                   \
              af[kk_c][ti], bfr[kk_c][tj], acc[ti][tj], 0, 0, 0);                  \
  }

  STAGE(0, 0);
  __syncthreads();                       // buf0 ready
  if (j.A2 != nullptr) {                 // K=512: 8 steps
#pragma unroll
    for (int t = 0; t < 8; ++t) {
      if (t < 7) STAGE((t + 1) & 1, t + 1);   // issue next-tile loads BEFORE compute
      COMPUTE(t & 1);
      if (t < 7) __syncthreads();             // drains vmcnt: next buf ready
    }
  } else {                               // K=256: 4 steps
#pragma unroll
    for (int t = 0; t < 4; ++t) {
      if (t < 3) STAGE((t + 1) & 1, t + 1);
      COMPUTE(t & 1);
      if (t < 3) __syncthreads();
    }
  }
#undef STAGE
#undef COMPUTE

  const int N = j.nx * 128;
  for (int ti = 0; ti < 4; ++ti)
    for (int tj = 0; tj < 4; ++tj)
      for (int r2 = 0; r2 < 4; ++r2) {
        int gm = bm + wm + ti * 16 + quad * 4 + r2;
        int gn = bn + wn + tj * 16 + row;
        float v = acc[ti][tj][r2];
        if (j.epi == 0) {
          j.out[(size_t)gm * N + gn] = f2b(v);
        } else if (j.epi == 1) {
          j.out[(size_t)gm * N + gn] = f2b(v + j.bias[gn]);
        } else {
          float s = 1.0f / (1.0f + expf(-(v + j.bias[gn])));
          size_t g = (size_t)gm * 2304;
          if (gn < 256) {
            j.gnode[g + gn] = s;           // slot 0 (z1)
            j.gnode[g + 512 + gn] = s;     // slot 2 (z2 == z1)
            j.z1b[(size_t)gm * 256 + gn] = f2b(s);
          } else {
            int d = gn - 256;
            j.gnode[g + 256 + d] = s;      // slot 1 (r)
            j.rb[(size_t)gm * 256 + d] = f2b(s);
          }
        }
      }
}

// ---------- mixture: cand -> softmax over k -> out ; score partial-sums ----------
// mode 1: 1-(p1+b)   mode 2: p1*p2+b   mode 3: p1 (bias pre-added in gemm epilogue)
struct MixJob {
  const ushort* P1; const ushort* P2;
  float* gnode; ushort* act; float* hnext; float* part;
  int mode;
};

__global__ __launch_bounds__(256)
void mixN_kernel(MixJob j0, MixJob j1, MixJob j2, const float* __restrict__ bias,
                 const float* __restrict__ Ws) {
  const int jb = blockIdx.x >> 12;
  const MixJob j = (jb == 0) ? j0 : (jb == 1) ? j1 : j2;
  const int lb = blockIdx.x & 4095;

  const int tid  = threadIdx.x;
  const int wave = tid >> 6;
  const int lane = tid & 63;
  const int row  = lb * 4 + wave;
  const int d0   = lane * 4;
  float c[4][4];
  float sp[4];
  float4 w4 = *(const float4*)(Ws + d0);
  float ws4[4] = {w4.x, w4.y, w4.z, w4.w};
  for (int k = 0; k < 4; ++k) {
    float p1[4];
    loadbf4(j.P1 + (size_t)row * 1024 + k * 256 + d0, p1);
    float v[4];
    if (j.mode == 3) {
      for (int i = 0; i < 4; ++i) v[i] = p1[i];
    } else {
      float4 bb = *(const float4*)(bias + k * 256 + d0);
      float bv[4] = {bb.x, bb.y, bb.z, bb.w};
      if (j.mode == 1) {
        for (int i = 0; i < 4; ++i) v[i] = 1.0f - (p1[i] + bv[i]);
      } else {
        float p2[4];
        loadbf4(j.P2 + (size_t)row * 1024 + k * 256 + d0, p2);
        for (int i = 0; i < 4; ++i) v[i] = p1[i] * p2[i] + bv[i];
      }
    }
    float s = 0.f;
    for (int i = 0; i < 4; ++i) { c[k][i] = v[i]; s += v[i] * ws4[i]; }
    sp[k] = s;
  }
  for (int m = 1; m < 64; m <<= 1)
    for (int k = 0; k < 4; ++k) sp[k] += __shfl_xor(sp[k], m, 64);
  float mx = fmaxf(fmaxf(sp[0], sp[1]), fmaxf(sp[2], sp[3]));
  float e0 = expf(sp[0] - mx), e1 = expf(sp[1] - mx), e2 = expf(sp[2] - mx), e3 = expf(sp[3] - mx);
  float inv = 1.0f / (e0 + e1 + e2 + e3);
  float w0 = e0 * inv, w1 = e1 * inv, w2 = e2 * inv, w3 = e3 * inv;
  float o[4];
  for (int i = 0; i < 4; ++i) o[i] = w0 * c[0][i] + w1 * c[1][i] + w2 * c[2][i] + w3 * c[3][i];
  size_t g = (size_t)row * 2304 + d0;
  for (int i = 0; i < 4; ++i) j.gnode[g + i] = o[i];
  if (j.act) *(uint2*)(j.act + (size_t)row * 256 + d0) = packbf4(o);
  if (j.hnext) { float4 ov = {o[0], o[1], o[2], o[3]}; *(float4*)(j.hnext + (size_t)row * 256 + d0) = ov; }
  __shared__ float sred[4][4];
  if (lane == 0) for (int k = 0; k < 4; ++k) sred[wave][k] = sp[k];
  __syncthreads();
  if (tid < 4)
    j.part[lb * 4 + tid] = sred[0][tid] + sred[1][tid] + sred[2][tid] + sred[3][tid];
}

// ---------- finalize: reduce score partials, argmax + margin, G_structure ----------
__global__ __launch_bounds__(256)
void fin_kernel(const float* __restrict__ part, float* __restrict__ gs,
                float* __restrict__ margins) {
  __shared__ float red[256][4];
  __shared__ float sfin[6][4];
  int tid = threadIdx.x;
  for (int si = 0; si < 6; ++si) {
    float a[4] = {0.f, 0.f, 0.f, 0.f};
    for (int i = 0; i < 16; ++i) {
      const float* p = part + ((size_t)si * 4096 + tid + 256 * i) * 4;
      for (int k = 0; k < 4; ++k) a[k] += p[k];
    }
    for (int k = 0; k < 4; ++k) red[tid][k] = a[k];
    __syncthreads();
    for (int st = 128; st >= 1; st >>= 1) {
      if (tid < st) for (int k = 0; k < 4; ++k) red[tid][k] += red[tid + st][k];
      __syncthreads();
    }
    if (tid == 0) for (int k = 0; k < 4; ++k) sfin[si][k] = red[0][k];
    __syncthreads();
  }
  if (tid == 0) {
    gs[0] = 0.f; gs[1] = 1.f; gs[2] = 0.f;
    for (int si = 0; si < 6; ++si) {
      float s[4] = {sfin[si][0], sfin[si][1], sfin[si][2], sfin[si][3]};
      int idx = 0; float best = s[0];
      for (int k = 1; k < 4; ++k) if (s[k] > best) { best = s[k]; idx = k; }
      float second = -3.4e38f;
      for (int k = 0; k < 4; ++k) if (k != idx) second = fmaxf(second, s[k]);
      gs[3 + si] = (float)idx;
      margins[si] = best - second;
    }
  }
}

extern "C" void kernel_launch(void* const* d_in, const int* in_sizes, int n_in,
                              void* d_out, int out_size, void* d_ws, size_t ws_size,
                              hipStream_t stream) {
  const float* x    = (const float*)d_in[0];
  const float* h    = (const float*)d_in[1];
  const float* L    = (const float*)d_in[2];
  const float* R    = (const float*)d_in[3];
  const float* bias = (const float*)d_in[4];
  const float* Ws   = (const float*)d_in[5];

  float* out        = (float*)d_out;
  float* out_hnext  = out;                          // 4,194,304
  float* out_gs     = out + 4194304;                // 9
  float* out_gnode  = out + 4194313;                // 16384*9*256
  float* out_marg   = out + 41943049;               // 6

  // workspace layout (bf16 as ushort)
  ushort* P0   = (ushort*)d_ws;                     // B*1024
  ushort* P1   = P0 + (size_t)BATCH * 1024;
  ushort* P2   = P1 + (size_t)BATCH * 1024;
  ushort* x2b  = P2 + (size_t)BATCH * 1024;
  ushort* h2b  = x2b + (size_t)BATCH * HID;
  ushort* z1b  = h2b + (size_t)BATCH * HID;
  ushort* rb   = z1b + (size_t)BATCH * HID;
  ushort* rhb  = rb  + (size_t)BATCH * HID;
  ushort* htb  = rhb + (size_t)BATCH * HID;
  ushort* omzb = htb + (size_t)BATCH * HID;
  ushort* ztb  = omzb + (size_t)BATCH * HID;
  ushort* z2hb = ztb + (size_t)BATCH * HID;
  ushort* Lt   = z2hb + (size_t)BATCH * HID;        // 1024*256
  ushort* Rt   = Lt + 1024 * 256;
  float*  part = (float*)(Rt + 1024 * 256);         // 6*4096*4 floats

  f2b2_kernel<<<8192, 256, 0, stream>>>(x, h, x2b, h2b);
  wt2_kernel<<<2048, 256, 0, stream>>>(L, R, Lt, Rt);

  GJob jz = {};   // filler

  // L3: G_sig = [x|h]@[L01;R01] (sig epilogue)  +  hL raw -> P0
  {
    GJob a = {x2b, h2b, Lt, Rt, nullptr, bias, out_gnode, z1b, rb, 4, 2, 512};
    GJob b = {h2b, nullptr, Lt, nullptr, P0, nullptr, nullptr, nullptr, nullptr, 8, 0, 1024};
    fgemm_kernel<<<1536, 256, 0, stream>>>(a, b, 512);
  }
  // L4: cand_rh = [h|r]@[L;R]+b -> P1   +   z1R raw -> P2
  {
    GJob a = {h2b, rb, Lt, Rt, P1, bias, nullptr, nullptr, nullptr, 8, 1, 1024};
    GJob b = {z1b, nullptr, Rt, nullptr, P2, nullptr, nullptr, nullptr, nullptr, 8, 0, 1024};
    fgemm_kernel<<<2048, 256, 0, stream>>>(a, b, 1024);
  }
  // L5: mixes {rh (mode3, P1)}, {omz (mode1, P2)}, {z2h (mode2, P0*P2)}
  {
    MixJob m0 = {P1, nullptr, out_gnode + 3 * 256, rhb,  nullptr, part + 0 * 16384, 3};
    MixJob m1 = {P2, nullptr, out_gnode + 5 * 256, omzb, nullptr, part + 2 * 16384, 1};
    MixJob m2 = {P0, P2,      out_gnode + 7 * 256, z2hb, nullptr, part + 4 * 16384, 2};
    mixN_kernel<<<12288, 256, 0, stream>>>(m0, m1, m2, bias, Ws);
  }
  // L6: cand_ht = [x|rh]@[L;R]+b -> P0
  {
    GJob a = {x2b, rhb, Lt, Rt, P0, bias, nullptr, nullptr, nullptr, 8, 1, 1024};
    fgemm_kernel<<<1024, 256, 0, stream>>>(a, jz, 1024);
  }
  // L7: mix ht (mode3, P0)
  {
    MixJob m0 = {P0, nullptr, out_gnode + 4 * 256, htb, nullptr, part + 1 * 16384, 3};
    MixJob mz = m0;
    mixN_kernel<<<4096, 256, 0, stream>>>(m0, mz, mz, bias, Ws);
  }
  // L8: htL raw -> P1   +   omzR raw -> P2
  {
    GJob a = {htb,  nullptr, Lt, nullptr, P1, nullptr, nullptr, nullptr, nullptr, 8, 0, 1024};
    GJob b = {omzb, nullptr, Rt, nullptr, P2, nullptr, nullptr, nullptr, nullptr, 8, 0, 1024};
    fgemm_kernel<<<2048, 256, 0, stream>>>(a, b, 1024);
  }
  // L9: mix zt (mode2, P1*P2)
  {
    MixJob m0 = {P1, P2, out_gnode + 6 * 256, ztb, nullptr, part + 3 * 16384, 2};
    MixJob mz = m0;
    mixN_kernel<<<4096, 256, 0, stream>>>(m0, mz, mz, bias, Ws);
  }
  // L10: cand_hn = [zt|z2h]@[L;R]+b -> P0
  {
    GJob a = {ztb, z2hb, Lt, Rt, P0, bias, nullptr, nullptr, nullptr, 8, 1, 1024};
    fgemm_kernel<<<1024, 256, 0, stream>>>(a, jz, 1024);
  }
  // L11: mix hn (mode3, P0) -> hnext f32
  {
    MixJob m0 = {P0, nullptr, out_gnode + 8 * 256, nullptr, out_hnext, part + 5 * 16384, 3};
    MixJob mz = m0;
    mixN_kernel<<<4096, 256, 0, stream>>>(m0, mz, mz, bias, Ws);
  }
  fin_kernel<<<1, 256, 0, stream>>>(part, out_gs, out_marg);
}

// Round 4
// 589.443 us; speedup vs baseline: 1.0253x; 1.0253x over previous
//
#include <hip/hip_runtime.h>

typedef __bf16 bf16_t;
typedef bf16_t bf16x8 __attribute__((ext_vector_type(8)));
typedef float f32x4 __attribute__((ext_vector_type(4)));

#define BATCH 16384
#define HID 256

template<int N> struct IC { static constexpr int v = N; };

// ---------- bf16 helpers (manual RNE, no header dependency) ----------
__device__ __forceinline__ ushort f2b(float f) {
  union { float f; unsigned u; } v; v.f = f;
  unsigned u = v.u;
  unsigned r = (u + 0x7fffu + ((u >> 16) & 1u)) >> 16;
  return (ushort)r;
}
__device__ __forceinline__ float b2f(ushort u) {
  union { unsigned u; float f; } v; v.u = ((unsigned)u) << 16; return v.f;
}
__device__ __forceinline__ void loadbf4(const ushort* __restrict__ p, float* o) {
  uint2 q = *(const uint2*)p;
  o[0] = b2f((ushort)(q.x & 0xffffu));
  o[1] = b2f((ushort)(q.x >> 16));
  o[2] = b2f((ushort)(q.y & 0xffffu));
  o[3] = b2f((ushort)(q.y >> 16));
}
__device__ __forceinline__ uint2 packbf4(const float* v) {
  uint2 q;
  q.x = (unsigned)f2b(v[0]) | ((unsigned)f2b(v[1]) << 16);
  q.y = (unsigned)f2b(v[2]) | ((unsigned)f2b(v[3]) << 16);
  return q;
}

// ---------- convert fp32 -> bf16 (x and h in one launch) ----------
__global__ __launch_bounds__(256)
void f2b2_kernel(const float* __restrict__ a, const float* __restrict__ b,
                 ushort* __restrict__ oa, ushort* __restrict__ ob) {
  int bid = blockIdx.x;
  const float* in = (bid < 4096) ? a : b;
  ushort* out     = (bid < 4096) ? oa : ob;
  int t = (bid & 4095) * 256 + threadIdx.x;
  float4 v = *(const float4*)(in + (size_t)t * 4);
  float q[4] = {v.x, v.y, v.z, v.w};
  *(uint2*)(out + (size_t)t * 4) = packbf4(q);
}

// ---------- build transposed bf16 weights: Wt[ksel*256+d][h] = W[ksel][h][d] ----------
__global__ __launch_bounds__(256)
void wt2_kernel(const float* __restrict__ L, const float* __restrict__ R,
                ushort* __restrict__ Lt, ushort* __restrict__ Rt) {
  int bid = blockIdx.x;
  const float* W = (bid < 1024) ? L : R;
  ushort* Wt     = (bid < 1024) ? Lt : Rt;
  int idx = (bid & 1023) * 256 + threadIdx.x;
  int c = idx >> 8, hh = idx & 255;
  int ks = c >> 8, d = c & 255;
  Wt[idx] = f2b(W[ks * 65536 + hh * 256 + d]);
}

// ---------- fused GEMM: P[M,N] = A@W (+ optional K-concat: A1@W1 + A2@W2) ----------
// 128x128 tile, BK=64. T3+T4 counted-vmcnt ring pipeline:
//   A-ring x3 (prefetch distance 2), B-ring x2 (distance 1), 80KB LDS, 2 blocks/CU.
//   Per step: s_barrier (WAR) -> STAGE_B(t+1), STAGE_A(t+2) -> s_waitcnt vmcnt(12)
//   (never 0 in main loop) -> s_barrier -> sched_barrier(0) -> setprio(1) MFMA setprio(0).
// global_load_lds(16B), XOR granule swizzle both-sides, per-job XCD-bijective block swizzle.
// Epilogues: 0=raw bf16, 1=+bias bf16 (cand), 2=sigmoid (z1/r/gnode slots 0,1,2).
struct GJob {
  const ushort* A1; const ushort* A2;   // A2 != null => K=512 concat (8 steps)
  const ushort* B1; const ushort* B2;   // B2 used for kt>=4
  ushort* out;
  const float* bias;
  float* gnode; ushort* z1b; ushort* rb;   // epi 2 only
  int nx;        // column tiles (4 -> N=512, 8 -> N=1024)
  int epi;
  int nblocks;   // nx * 128
};

__global__ __launch_bounds__(256, 2)
void fgemm_kernel(GJob j0, GJob j1, int split) {
  __shared__ __align__(16) ushort As[3][128 * 64];   // 48 KB ring
  __shared__ __align__(16) ushort Bs[2][128 * 64];   // 32 KB ring

  const int bid  = blockIdx.x;
  const GJob j   = (bid < split) ? j0 : j1;
  const int lbid = (bid < split) ? bid : bid - split;

  const int tid  = threadIdx.x;
  const int lane = tid & 63;
  const int wave = tid >> 6;

  // per-job XCD-bijective swizzle (nblocks % 8 == 0 for all jobs; split % 8 == 0)
  const int q   = j.nblocks >> 3;
  const int id2 = (lbid & 7) * q + (lbid >> 3);
  int cn, cm;
  if (j.nx == 8) { cn = id2 & 7; cm = id2 >> 3; }
  else           { cn = id2 & 3; cm = id2 >> 2; }
  const int bm = cm * 128;
  const int bn = cn * 128;

  const int wm   = (wave >> 1) * 64;
  const int wn   = (wave & 1) * 64;
  const int row  = lane & 15;
  const int quad = lane >> 4;

  // staging geometry: 16 chunks of 1KB (8 rows x 64 bf16); wave w owns chunks w*4..w*4+3
  const int r_s = lane >> 3;
  const int g_s = lane & 7;
  const int gsw = g_s ^ r_s;   // inverse-swizzled source granule

  f32x4 acc[4][4] = {};

#define VMW(n) asm volatile("s_waitcnt vmcnt(" #n ")" ::: "memory")

#define STAGE_A(buf, kt)                                                           \
  {                                                                                \
    const int bufs_a = (buf);                                                      \
    const int kts_a  = (kt);                                                       \
    const ushort* Ab = (kts_a < 4) ? j.A1 : j.A2;                                  \
    const int k0a = (kts_a & 3) * 64;                                              \
    for (int i_sa = 0; i_sa < 4; ++i_sa) {                                         \
      const int cia = wave * 4 + i_sa;                                             \
      const int ra  = cia * 8 + r_s;                                               \
      __builtin_amdgcn_global_load_lds(                                            \
          (const __attribute__((address_space(1))) void*)(Ab + (size_t)(bm + ra) * 256 + k0a + gsw * 8), \
          (__attribute__((address_space(3))) void*)&As[bufs_a][cia * 512], 16, 0, 0); \
    }                                                                              \
  }

#define STAGE_B(buf, kt)                                                           \
  {                                                                                \
    const int bufs_b = (buf);                                                      \
    const int kts_b  = (kt);                                                       \
    const ushort* Bb = (kts_b < 4) ? j.B1 : j.B2;                                  \
    const int k0b = (kts_b & 3) * 64;                                              \
    for (int i_sb = 0; i_sb < 4; ++i_sb) {                                         \
      const int cib = wave * 4 + i_sb;                                             \
      const int rb_ = cib * 8 + r_s;                                               \
      __builtin_amdgcn_global_load_lds(                                            \
          (const __attribute__((address_space(1))) void*)(Bb + (size_t)(bn + rb_) * 256 + k0b + gsw * 8), \
          (__attribute__((address_space(3))) void*)&Bs[bufs_b][cib * 512], 16, 0, 0); \
    }                                                                              \
  }

#define COMPUTE(abuf, bbuf)                                                        \
  {                                                                                \
    const int abc = (abuf);                                                        \
    const int bbc = (bbuf);                                                        \
    bf16x8 af[2][4], bfr[2][4];                                                    \
    for (int kk_c = 0; kk_c < 2; ++kk_c)                                           \
      for (int fr_c = 0; fr_c < 4; ++fr_c) {                                       \
        const int ar = wm + fr_c * 16 + row;                                       \
        const int ga = (kk_c * 4 + quad) ^ (ar & 7);                               \
        af[kk_c][fr_c] = *(const bf16x8*)&As[abc][ar * 64 + ga * 8];               \
        const int br = wn + fr_c * 16 + row;                                       \
        const int gb = (kk_c * 4 + quad) ^ (br & 7);                               \
        bfr[kk_c][fr_c] = *(const bf16x8*)&Bs[bbc][br * 64 + gb * 8];              \
      }                                                                            \
    __builtin_amdgcn_s_setprio(1);                                                 \
    for (int kk_c = 0; kk_c < 2; ++kk_c)                                           \
      for (int ti = 0; ti < 4; ++ti)                                               \
        for (int tj = 0; tj < 4; ++tj)                                             \
          acc[ti][tj] = __builtin_amdgcn_mfma_f32_16x16x32_bf16(                   \
              af[kk_c][ti], bfr[kk_c][tj], acc[ti][tj], 0, 0, 0);                  \
    __builtin_amdgcn_s_setprio(0);                                                 \
  }

  // counted-vmcnt ring pipeline. FIFO audit (groups of 4 loads per wave):
  //   prologue: A0,B0,A1 (12 outstanding)
  //   step t:   issue B(t+1),A(t+2) -> 20; wait vmcnt(12) retires {A(t),B(t)}
  //   t==nt-2:  issue B(nt-1) only -> 16; wait vmcnt(8)
  //   t==nt-1:  no issue; wait vmcnt(0)
  auto PIPE = [&](auto ntc) {
    constexpr int nt = decltype(ntc)::v;
    STAGE_A(0, 0);
    STAGE_B(0, 0);
    STAGE_A(1, 1);
#pragma unroll
    for (int t = 0; t < nt; ++t) {
      __builtin_amdgcn_s_barrier();            // WAR: buffers about to be overwritten are free
      if (t + 1 < nt) STAGE_B((t + 1) & 1, t + 1);
      if (t + 2 < nt) STAGE_A((t + 2) % 3, t + 2);
      if (t < nt - 2)      { VMW(12); }
      else if (t == nt - 2){ VMW(8); }
      else                 { VMW(0); }
      __builtin_amdgcn_s_barrier();            // all waves' stage-t data landed
      __builtin_amdgcn_sched_barrier(0);       // pin ds_reads behind the wait (rule 18)
      COMPUTE(t % 3, t & 1);
      __builtin_amdgcn_sched_barrier(0);       // keep compute cluster inside its phase
    }
  };
  if (j.A2 != nullptr) PIPE(IC<8>{});
  else                 PIPE(IC<4>{});

#undef STAGE_A
#undef STAGE_B
#undef COMPUTE
#undef VMW

  const int N = j.nx * 128;
  for (int ti = 0; ti < 4; ++ti)
    for (int tj = 0; tj < 4; ++tj)
      for (int r2 = 0; r2 < 4; ++r2) {
        int gm = bm + wm + ti * 16 + quad * 4 + r2;
        int gn = bn + wn + tj * 16 + row;
        float v = acc[ti][tj][r2];
        if (j.epi == 0) {
          j.out[(size_t)gm * N + gn] = f2b(v);
        } else if (j.epi == 1) {
          j.out[(size_t)gm * N + gn] = f2b(v + j.bias[gn]);
        } else {
          float s = 1.0f / (1.0f + expf(-(v + j.bias[gn])));
          size_t g = (size_t)gm * 2304;
          if (gn < 256) {
            j.gnode[g + gn] = s;           // slot 0 (z1)
            j.gnode[g + 512 + gn] = s;     // slot 2 (z2 == z1)
            j.z1b[(size_t)gm * 256 + gn] = f2b(s);
          } else {
            int d = gn - 256;
            j.gnode[g + 256 + d] = s;      // slot 1 (r)
            j.rb[(size_t)gm * 256 + d] = f2b(s);
          }
        }
      }
}

// ---------- mixture: cand -> softmax over k -> out ; score partial-sums ----------
// mode 1: 1-(p1+b)   mode 2: p1*p2+b   mode 3: p1 (bias pre-added in gemm epilogue)
struct MixJob {
  const ushort* P1; const ushort* P2;
  float* gnode; ushort* act; float* hnext; float* part;
  int mode;
};

__global__ __launch_bounds__(256)
void mixN_kernel(MixJob j0, MixJob j1, MixJob j2, const float* __restrict__ bias,
                 const float* __restrict__ Ws) {
  const int jb = blockIdx.x >> 12;
  const MixJob j = (jb == 0) ? j0 : (jb == 1) ? j1 : j2;
  const int lb = blockIdx.x & 4095;

  const int tid  = threadIdx.x;
  const int wave = tid >> 6;
  const int lane = tid & 63;
  const int row  = lb * 4 + wave;
  const int d0   = lane * 4;
  float c[4][4];
  float sp[4];
  float4 w4 = *(const float4*)(Ws + d0);
  float ws4[4] = {w4.x, w4.y, w4.z, w4.w};
  for (int k = 0; k < 4; ++k) {
    float p1[4];
    loadbf4(j.P1 + (size_t)row * 1024 + k * 256 + d0, p1);
    float v[4];
    if (j.mode == 3) {
      for (int i = 0; i < 4; ++i) v[i] = p1[i];
    } else {
      float4 bb = *(const float4*)(bias + k * 256 + d0);
      float bv[4] = {bb.x, bb.y, bb.z, bb.w};
      if (j.mode == 1) {
        for (int i = 0; i < 4; ++i) v[i] = 1.0f - (p1[i] + bv[i]);
      } else {
        float p2[4];
        loadbf4(j.P2 + (size_t)row * 1024 + k * 256 + d0, p2);
        for (int i = 0; i < 4; ++i) v[i] = p1[i] * p2[i] + bv[i];
      }
    }
    float s = 0.f;
    for (int i = 0; i < 4; ++i) { c[k][i] = v[i]; s += v[i] * ws4[i]; }
    sp[k] = s;
  }
  for (int m = 1; m < 64; m <<= 1)
    for (int k = 0; k < 4; ++k) sp[k] += __shfl_xor(sp[k], m, 64);
  float mx = fmaxf(fmaxf(sp[0], sp[1]), fmaxf(sp[2], sp[3]));
  float e0 = expf(sp[0] - mx), e1 = expf(sp[1] - mx), e2 = expf(sp[2] - mx), e3 = expf(sp[3] - mx);
  float inv = 1.0f / (e0 + e1 + e2 + e3);
  float w0 = e0 * inv, w1 = e1 * inv, w2 = e2 * inv, w3 = e3 * inv;
  float o[4];
  for (int i = 0; i < 4; ++i) o[i] = w0 * c[0][i] + w1 * c[1][i] + w2 * c[2][i] + w3 * c[3][i];
  size_t g = (size_t)row * 2304 + d0;
  for (int i = 0; i < 4; ++i) j.gnode[g + i] = o[i];
  if (j.act) *(uint2*)(j.act + (size_t)row * 256 + d0) = packbf4(o);
  if (j.hnext) { float4 ov = {o[0], o[1], o[2], o[3]}; *(float4*)(j.hnext + (size_t)row * 256 + d0) = ov; }
  __shared__ float sred[4][4];
  if (lane == 0) for (int k = 0; k < 4; ++k) sred[wave][k] = sp[k];
  __syncthreads();
  if (tid < 4)
    j.part[lb * 4 + tid] = sred[0][tid] + sred[1][tid] + sred[2][tid] + sred[3][tid];
}

// ---------- finalize: reduce score partials, argmax + margin, G_structure ----------
__global__ __launch_bounds__(256)
void fin_kernel(const float* __restrict__ part, float* __restrict__ gs,
                float* __restrict__ margins) {
  __shared__ float red[256][4];
  __shared__ float sfin[6][4];
  int tid = threadIdx.x;
  for (int si = 0; si < 6; ++si) {
    float a[4] = {0.f, 0.f, 0.f, 0.f};
    for (int i = 0; i < 16; ++i) {
      const float* p = part + ((size_t)si * 4096 + tid + 256 * i) * 4;
      for (int k = 0; k < 4; ++k) a[k] += p[k];
    }
    for (int k = 0; k < 4; ++k) red[tid][k] = a[k];
    __syncthreads();
    for (int st = 128; st >= 1; st >>= 1) {
      if (tid < st) for (int k = 0; k < 4; ++k) red[tid][k] += red[tid + st][k];
      __syncthreads();
    }
    if (tid == 0) for (int k = 0; k < 4; ++k) sfin[si][k] = red[0][k];
    __syncthreads();
  }
  if (tid == 0) {
    gs[0] = 0.f; gs[1] = 1.f; gs[2] = 0.f;
    for (int si = 0; si < 6; ++si) {
      float s[4] = {sfin[si][0], sfin[si][1], sfin[si][2], sfin[si][3]};
      int idx = 0; float best = s[0];
      for (int k = 1; k < 4; ++k) if (s[k] > best) { best = s[k]; idx = k; }
      float second = -3.4e38f;
      for (int k = 0; k < 4; ++k) if (k != idx) second = fmaxf(second, s[k]);
      gs[3 + si] = (float)idx;
      margins[si] = best - second;
    }
  }
}

extern "C" void kernel_launch(void* const* d_in, const int* in_sizes, int n_in,
                              void* d_out, int out_size, void* d_ws, size_t ws_size,
                              hipStream_t stream) {
  const float* x    = (const float*)d_in[0];
  const float* h    = (const float*)d_in[1];
  const float* L    = (const float*)d_in[2];
  const float* R    = (const float*)d_in[3];
  const float* bias = (const float*)d_in[4];
  const float* Ws   = (const float*)d_in[5];

  float* out        = (float*)d_out;
  float* out_hnext  = out;                          // 4,194,304
  float* out_gs     = out + 4194304;                // 9
  float* out_gnode  = out + 4194313;                // 16384*9*256
  float* out_marg   = out + 41943049;               // 6

  // workspace layout (bf16 as ushort)
  ushort* P0   = (ushort*)d_ws;                     // B*1024
  ushort* P1   = P0 + (size_t)BATCH * 1024;
  ushort* P2   = P1 + (size_t)BATCH * 1024;
  ushort* x2b  = P2 + (size_t)BATCH * 1024;
  ushort* h2b  = x2b + (size_t)BATCH * HID;
  ushort* z1b  = h2b + (size_t)BATCH * HID;
  ushort* rb   = z1b + (size_t)BATCH * HID;
  ushort* rhb  = rb  + (size_t)BATCH * HID;
  ushort* htb  = rhb + (size_t)BATCH * HID;
  ushort* omzb = htb + (size_t)BATCH * HID;
  ushort* ztb  = omzb + (size_t)BATCH * HID;
  ushort* z2hb = ztb + (size_t)BATCH * HID;
  ushort* Lt   = z2hb + (size_t)BATCH * HID;        // 1024*256
  ushort* Rt   = Lt + 1024 * 256;
  float*  part = (float*)(Rt + 1024 * 256);         // 6*4096*4 floats

  f2b2_kernel<<<8192, 256, 0, stream>>>(x, h, x2b, h2b);
  wt2_kernel<<<2048, 256, 0, stream>>>(L, R, Lt, Rt);

  GJob jz = {};   // filler

  // L3: G_sig = [x|h]@[L01;R01] (sig epilogue)  +  hL raw -> P0
  {
    GJob a = {x2b, h2b, Lt, Rt, nullptr, bias, out_gnode, z1b, rb, 4, 2, 512};
    GJob b = {h2b, nullptr, Lt, nullptr, P0, nullptr, nullptr, nullptr, nullptr, 8, 0, 1024};
    fgemm_kernel<<<1536, 256, 0, stream>>>(a, b, 512);
  }
  // L4: cand_rh = [h|r]@[L;R]+b -> P1   +   z1R raw -> P2
  {
    GJob a = {h2b, rb, Lt, Rt, P1, bias, nullptr, nullptr, nullptr, 8, 1, 1024};
    GJob b = {z1b, nullptr, Rt, nullptr, P2, nullptr, nullptr, nullptr, nullptr, 8, 0, 1024};
    fgemm_kernel<<<2048, 256, 0, stream>>>(a, b, 1024);
  }
  // L5: mixes {rh (mode3, P1)}, {omz (mode1, P2)}, {z2h (mode2, P0*P2)}
  {
    MixJob m0 = {P1, nullptr, out_gnode + 3 * 256, rhb,  nullptr, part + 0 * 16384, 3};
    MixJob m1 = {P2, nullptr, out_gnode + 5 * 256, omzb, nullptr, part + 2 * 16384, 1};
    MixJob m2 = {P0, P2,      out_gnode + 7 * 256, z2hb, nullptr, part + 4 * 16384, 2};
    mixN_kernel<<<12288, 256, 0, stream>>>(m0, m1, m2, bias, Ws);
  }
  // L6: cand_ht = [x|rh]@[L;R]+b -> P0
  {
    GJob a = {x2b, rhb, Lt, Rt, P0, bias, nullptr, nullptr, nullptr, 8, 1, 1024};
    fgemm_kernel<<<1024, 256, 0, stream>>>(a, jz, 1024);
  }
  // L7: mix ht (mode3, P0)
  {
    MixJob m0 = {P0, nullptr, out_gnode + 4 * 256, htb, nullptr, part + 1 * 16384, 3};
    MixJob mz = m0;
    mixN_kernel<<<4096, 256, 0, stream>>>(m0, mz, mz, bias, Ws);
  }
  // L8: htL raw -> P1   +   omzR raw -> P2
  {
    GJob a = {htb,  nullptr, Lt, nullptr, P1, nullptr, nullptr, nullptr, nullptr, 8, 0, 1024};
    GJob b = {omzb, nullptr, Rt, nullptr, P2, nullptr, nullptr, nullptr, nullptr, 8, 0, 1024};
    fgemm_kernel<<<2048, 256, 0, stream>>>(a, b, 1024);
  }
  // L9: mix zt (mode2, P1*P2)
  {
    MixJob m0 = {P1, P2, out_gnode + 6 * 256, ztb, nullptr, part + 3 * 16384, 2};
    MixJob mz = m0;
    mixN_kernel<<<4096, 256, 0, stream>>>(m0, mz, mz, bias, Ws);
  }
  // L10: cand_hn = [zt|z2h]@[L;R]+b -> P0
  {
    GJob a = {ztb, z2hb, Lt, Rt, P0, bias, nullptr, nullptr, nullptr, 8, 1, 1024};
    fgemm_kernel<<<1024, 256, 0, stream>>>(a, jz, 1024);
  }
  // L11: mix hn (mode3, P0) -> hnext f32
  {
    MixJob m0 = {P0, nullptr, out_gnode + 8 * 256, nullptr, out_hnext, part + 5 * 16384, 3};
    MixJob mz = m0;
    mixN_kernel<<<4096, 256, 0, stream>>>(m0, mz, mz, bias, Ws);
  }
  fin_kernel<<<1, 256, 0, stream>>>(part, out_gs, out_marg);
}